// Round 6
// baseline (385.826 us; speedup 1.0000x reference)
//
#include <hip/hip_runtime.h>
#include <hip/hip_fp16.h>
#include <math.h>

typedef _Float16 f16;
typedef _Float16 f16x2 __attribute__((ext_vector_type(2)));
typedef _Float16 f16x8 __attribute__((ext_vector_type(8)));
typedef float f32x4 __attribute__((ext_vector_type(4)));
typedef unsigned char u8;

#define HDIM 256
#define TST 128
#define OUTD 10
#define S2LE 2.8853900817779268f   // 2*log2(e)

static __device__ __forceinline__ f16x2 pkrtz(float a, float b) {
  auto r = __builtin_amdgcn_cvt_pkrtz(a, b);
  return *(f16x2*)&r;
}

// R5 geometry (4 waves/block, wave owns 64 hidden rows x 32 batch cols,
// 512 blocks = one residency round) with the VALU-lean R3 algebra:
//   y_scaled = rs*(Wg@tv) + [dd - rs*mu*RSg],  next frag = f16(tv).
// t-loop unrolled x2 -> compile-time dbuf parity -> immediate-offset LDS.
__global__ __launch_bounds__(256, 2) void rnn_kernel(
    const float* __restrict__ x,
    const float* __restrict__ embed_w,
    const float* __restrict__ embed_b,
    const float* __restrict__ update_w,
    const float* __restrict__ update_b,
    const float* __restrict__ gamma,
    const float* __restrict__ beta,
    const float* __restrict__ out_w,
    const float* __restrict__ out_b,
    float* __restrict__ out)
{
  __shared__ __align__(16) f16   sFR[2][2][8][64][8]; // 32 KB frag dbuf; overlays: T0 (init), sOut (epi)
  __shared__ __align__(16) float sD1[10 * 260];       // 10.4 KB; overlay epi: sOW
  __shared__ __align__(16) float sBW[HDIM];
  __shared__ __align__(16) float sRSg[HDIM];
  __shared__ __align__(16) float sST[2][32][12];
  __shared__ float sOB[16];
  __shared__ u8    sXb[TST][32];

  const int tid = threadIdx.x;
  const int w  = tid >> 6;      // 0..3
  const int l  = tid & 63;
  const int q  = l >> 4;
  const int ml = l & 15;
  const int base = blockIdx.x * 32;
  const int nb = w * 64 + q * 4;

  float* T0 = (float*)&sFR[0][0][0][0][0];   // [256][10] init-only

  // ---------- P1 ----------
  {
    float ew = embed_w[tid], eb = embed_b[tid];
    #pragma unroll
    for (int xv = 0; xv < 10; xv++)
      T0[tid * 10 + xv] = tanhf((float)xv * ew + eb);
  }
  for (int idx = tid; idx < 32 * TST; idx += 256) {
    int col = idx >> 7, tt = idx & 127;
    sXb[tt][col] = (u8)(int)x[(size_t)(base + col) * TST + tt];
  }
  if (tid < 16) {
    float v = 0.f;
    if (tid < OUTD) {
      v = out_b[tid];
      const float* orow = out_w + tid * HDIM;
      for (int k = 0; k < HDIM; k += 4) {
        float4 wv = *(const float4*)(orow + k);
        float4 bv = *(const float4*)(beta + k);
        v = fmaf(wv.x, bv.x, fmaf(wv.y, bv.y, fmaf(wv.z, bv.z, fmaf(wv.w, bv.w, v))));
      }
    }
    sOB[tid] = v;
  }
  __syncthreads();

  // ---------- P2: per-n tables (n = tid) ----------
  {
    const int n = tid;
    const float* wrow = update_w + n * HDIM;
    float ty[10];
    #pragma unroll
    for (int xv = 0; xv < 10; xv++) ty[xv] = 0.f;
    float bw = 0.f, rsg = 0.f;
    for (int k = 0; k < HDIM; k += 4) {
      float4 wv4 = *(const float4*)(wrow + k);
      float4 b4  = *(const float4*)(beta + k);
      float4 g4  = *(const float4*)(gamma + k);
      bw  = fmaf(wv4.x, b4.x, fmaf(wv4.y, b4.y, fmaf(wv4.z, b4.z, fmaf(wv4.w, b4.w, bw))));
      rsg = fmaf(wv4.x, S2LE * g4.x, fmaf(wv4.y, S2LE * g4.y,
            fmaf(wv4.z, S2LE * g4.z, fmaf(wv4.w, S2LE * g4.w, rsg))));
      #pragma unroll
      for (int kk = 0; kk < 4; kk++) {
        float wv = ((const float*)&wv4)[kk];
        const float* t0r = T0 + (k + kk) * 10;
        #pragma unroll
        for (int xv = 0; xv < 10; xv++) ty[xv] = fmaf(wv, t0r[xv], ty[xv]);
      }
    }
    float ubn = update_b[n];
    sBW[n]  = S2LE * bw;
    sRSg[n] = rsg;
    #pragma unroll
    for (int xv = 0; xv < 10; xv++)
      sD1[xv * 260 + n] = S2LE * (ty[xv] + ubn + bw);
  }
  __syncthreads();

  // ---------- W_g fragments (128 regs) ----------
  f16x8 wf[4][8];
  #pragma unroll
  for (int c = 0; c < 8; c++) {
    const int k0 = c * 32 + q * 4;
    float4 g0 = *(const float4*)(gamma + k0);
    float4 g1 = *(const float4*)(gamma + k0 + 16);
    #pragma unroll
    for (int nt = 0; nt < 4; nt++) {
      const float* wrow = update_w + (w * 64 + nt * 16 + ml) * HDIM;
      float4 a0 = *(const float4*)(wrow + k0);
      float4 a1 = *(const float4*)(wrow + k0 + 16);
      f16x8 f;
      f[0]=(f16)(S2LE*g0.x*a0.x); f[1]=(f16)(S2LE*g0.y*a0.y);
      f[2]=(f16)(S2LE*g0.z*a0.z); f[3]=(f16)(S2LE*g0.w*a0.w);
      f[4]=(f16)(S2LE*g1.x*a1.x); f[5]=(f16)(S2LE*g1.y*a1.y);
      f[6]=(f16)(S2LE*g1.z*a1.z); f[7]=(f16)(S2LE*g1.w*a1.w);
      wf[nt][c] = f;
    }
  }
  f32x4 rsgr[4];
  #pragma unroll
  for (int nt = 0; nt < 4; nt++)
    rsgr[nt] = *(const f32x4*)(sRSg + nb + nt * 16);

  // ---------- prologue t=0: y0 = D1[xv0] - BW ----------
  {
    float p1g_[2], p2g_[2];
    #pragma unroll
    for (int g = 0; g < 2; g++) {
      const int xv0 = (int)sXb[0][g * 16 + ml];
      const float* dp = sD1 + xv0 * 260;
      float p1 = 0.f, p2 = 0.f;
      #pragma unroll
      for (int cp = 0; cp < 2; cp++) {
        union { f16x8 v8; f16x2 v2[4]; } pk;
        #pragma unroll
        for (int h = 0; h < 2; h++) {
          const int nt = 2 * cp + h;
          f32x4 dd = *(const f32x4*)(dp + nb + nt * 16);
          f32x4 bw = *(const f32x4*)(sBW + nb + nt * 16);
          float tq[4];
          #pragma unroll
          for (int r = 0; r < 4; r++) {
            float y = dd[r] - bw[r];
            float e = __builtin_amdgcn_exp2f(y);
            float tv = fmaf(-2.f, __builtin_amdgcn_rcpf(e + 1.f), 1.f);
            tq[r] = tv; p1 += tv; p2 = fmaf(tv, tv, p2);
          }
          pk.v2[2 * h]     = pkrtz(tq[0], tq[1]);
          pk.v2[2 * h + 1] = pkrtz(tq[2], tq[3]);
        }
        *(f16x8*)&sFR[0][g][2 * w + cp][l][0] = pk.v8;
      }
      p1g_[g] = p1; p2g_[g] = p2;
    }
    #pragma unroll
    for (int g = 0; g < 2; g++) {
      p1g_[g] += __shfl_xor(p1g_[g], 16, 64); p2g_[g] += __shfl_xor(p2g_[g], 16, 64);
      p1g_[g] += __shfl_xor(p1g_[g], 32, 64); p2g_[g] += __shfl_xor(p2g_[g], 32, 64);
    }
    if (l < 32) {
      int col = (l < 16) ? ml : (16 + ml);
      float2 v2 = (l < 16) ? make_float2(p1g_[0], p2g_[0]) : make_float2(p1g_[1], p2g_[1]);
      *(float2*)&sST[0][col][2 * w] = v2;
    }
    __syncthreads();
  }

#define MM8(CC, C0, C1, N0, N1)                                                \
    {                                                                          \
      if ((CC) < 7) {                                                          \
        N0 = *(const f16x8*)(fb0_ + ((CC) + 1) * 512 + l * 8);                 \
        N1 = *(const f16x8*)(fb1_ + ((CC) + 1) * 512 + l * 8);                 \
      }                                                                        \
      acc_[0][0] = __builtin_amdgcn_mfma_f32_16x16x32_f16(wf[0][CC], C0, acc_[0][0],0,0,0); \
      acc_[0][1] = __builtin_amdgcn_mfma_f32_16x16x32_f16(wf[1][CC], C0, acc_[0][1],0,0,0); \
      acc_[0][2] = __builtin_amdgcn_mfma_f32_16x16x32_f16(wf[2][CC], C0, acc_[0][2],0,0,0); \
      acc_[0][3] = __builtin_amdgcn_mfma_f32_16x16x32_f16(wf[3][CC], C0, acc_[0][3],0,0,0); \
      acc_[1][0] = __builtin_amdgcn_mfma_f32_16x16x32_f16(wf[0][CC], C1, acc_[1][0],0,0,0); \
      acc_[1][1] = __builtin_amdgcn_mfma_f32_16x16x32_f16(wf[1][CC], C1, acc_[1][1],0,0,0); \
      acc_[1][2] = __builtin_amdgcn_mfma_f32_16x16x32_f16(wf[2][CC], C1, acc_[1][2],0,0,0); \
      acc_[1][3] = __builtin_amdgcn_mfma_f32_16x16x32_f16(wf[3][CC], C1, acc_[1][3],0,0,0); \
    }

#define STEP(T, P, PP)                                                         \
  {                                                                            \
    const float* st0_ = &sST[PP][ml][0];                                       \
    const float* st1_ = &sST[PP][16 + ml][0];                                  \
    f32x4 u0_ = *(const f32x4*)(st0_);                                         \
    f32x4 u1_ = *(const f32x4*)(st0_ + 4);                                     \
    f32x4 v0_ = *(const f32x4*)(st1_);                                         \
    f32x4 v1_ = *(const f32x4*)(st1_ + 4);                                     \
    const int xva_ = (int)sXb[T][ml];                                          \
    const int xvb_ = (int)sXb[T][16 + ml];                                     \
    const f16* fb0_ = &sFR[PP][0][0][0][0];                                    \
    const f16* fb1_ = &sFR[PP][1][0][0][0];                                    \
    const float* dpa_ = sD1 + xva_ * 260 + nb;                                 \
    const float* dpb_ = sD1 + xvb_ * 260 + nb;                                 \
    f32x4 dda_[4], ddb_[4];                                                    \
    _Pragma("unroll") for (int n_ = 0; n_ < 4; n_++) {                         \
      dda_[n_] = *(const f32x4*)(dpa_ + n_ * 16);                              \
      ddb_[n_] = *(const f32x4*)(dpb_ + n_ * 16);                              \
    }                                                                          \
    f16x8 rA0_ = *(const f16x8*)(fb0_ + l * 8);                                \
    f16x8 rA1_ = *(const f16x8*)(fb1_ + l * 8);                                \
    f16x8 rB0_, rB1_;                                                          \
    f32x4 acc_[2][4];                                                          \
    _Pragma("unroll") for (int g_ = 0; g_ < 2; g_++)                           \
      _Pragma("unroll") for (int n_ = 0; n_ < 4; n_++)                         \
        acc_[g_][n_] = (f32x4){0.f, 0.f, 0.f, 0.f};                            \
    __builtin_amdgcn_s_setprio(1);                                             \
    MM8(0, rA0_, rA1_, rB0_, rB1_)                                             \
    MM8(1, rB0_, rB1_, rA0_, rA1_)                                             \
    MM8(2, rA0_, rA1_, rB0_, rB1_)                                             \
    MM8(3, rB0_, rB1_, rA0_, rA1_)                                             \
    MM8(4, rA0_, rA1_, rB0_, rB1_)                                             \
    MM8(5, rB0_, rB1_, rA0_, rA1_)                                             \
    MM8(6, rA0_, rA1_, rB0_, rB1_)                                             \
    MM8(7, rB0_, rB1_, rA0_, rA1_)                                             \
    __builtin_amdgcn_s_setprio(0);                                             \
    float s1a_ = (u0_[0] + u0_[2]) + (u1_[0] + u1_[2]);                        \
    float s2a_ = (u0_[1] + u0_[3]) + (u1_[1] + u1_[3]);                        \
    float s1b_ = (v0_[0] + v0_[2]) + (v1_[0] + v1_[2]);                        \
    float s2b_ = (v0_[1] + v0_[3]) + (v1_[1] + v1_[3]);                        \
    float mua_ = s1a_ * (1.f / 256.f);                                         \
    float rsa_ = __frsqrt_rn(fmaf(s2a_, 1.f / 256.f, -mua_ * mua_) + 1e-5f);   \
    float mub_ = s1b_ * (1.f / 256.f);                                         \
    float rsb_ = __frsqrt_rn(fmaf(s2b_, 1.f / 256.f, -mub_ * mub_) + 1e-5f);   \
    float rma_ = rsa_ * mua_;                                                  \
    float rmb_ = rsb_ * mub_;                                                  \
    float p1a_ = 0.f, p2a_ = 0.f, p1b_ = 0.f, p2b_ = 0.f;                      \
    _Pragma("unroll") for (int cp_ = 0; cp_ < 2; cp_++) {                      \
      union { f16x8 v8; f16x2 v2[4]; } ka_, kb_;                               \
      _Pragma("unroll") for (int h_ = 0; h_ < 2; h_++) {                       \
        const int nt_ = 2 * cp_ + h_;                                          \
        float ta_[4], tb_[4];                                                  \
        _Pragma("unroll") for (int r_ = 0; r_ < 4; r_++) {                     \
          float ya_ = fmaf(rsa_, acc_[0][nt_][r_],                             \
                       fmaf(-rma_, rsgr[nt_][r_], dda_[nt_][r_]));             \
          float ea_ = __builtin_amdgcn_exp2f(ya_);                             \
          float va_ = fmaf(-2.f, __builtin_amdgcn_rcpf(ea_ + 1.f), 1.f);       \
          ta_[r_] = va_; p1a_ += va_; p2a_ = fmaf(va_, va_, p2a_);             \
          float yb_ = fmaf(rsb_, acc_[1][nt_][r_],                             \
                       fmaf(-rmb_, rsgr[nt_][r_], ddb_[nt_][r_]));             \
          float eb_ = __builtin_amdgcn_exp2f(yb_);                             \
          float vb_ = fmaf(-2.f, __builtin_amdgcn_rcpf(eb_ + 1.f), 1.f);       \
          tb_[r_] = vb_; p1b_ += vb_; p2b_ = fmaf(vb_, vb_, p2b_);             \
        }                                                                      \
        ka_.v2[2 * h_]     = pkrtz(ta_[0], ta_[1]);                            \
        ka_.v2[2 * h_ + 1] = pkrtz(ta_[2], ta_[3]);                            \
        kb_.v2[2 * h_]     = pkrtz(tb_[0], tb_[1]);                            \
        kb_.v2[2 * h_ + 1] = pkrtz(tb_[2], tb_[3]);                            \
      }                                                                        \
      *(f16x8*)&sFR[P][0][2 * w + cp_][l][0] = ka_.v8;                         \
      *(f16x8*)&sFR[P][1][2 * w + cp_][l][0] = kb_.v8;                         \
    }                                                                          \
    p1a_ += __shfl_xor(p1a_, 16, 64); p2a_ += __shfl_xor(p2a_, 16, 64);        \
    p1a_ += __shfl_xor(p1a_, 32, 64); p2a_ += __shfl_xor(p2a_, 32, 64);        \
    p1b_ += __shfl_xor(p1b_, 16, 64); p2b_ += __shfl_xor(p2b_, 16, 64);        \
    p1b_ += __shfl_xor(p1b_, 32, 64); p2b_ += __shfl_xor(p2b_, 32, 64);        \
    if (l < 32) {                                                              \
      int col_ = (l < 16) ? ml : (16 + ml);                                    \
      float2 w2_ = (l < 16) ? make_float2(p1a_, p2a_)                          \
                            : make_float2(p1b_, p2b_);                         \
      *(float2*)&sST[P][col_][2 * w] = w2_;                                    \
    }                                                                          \
    __syncthreads();                                                           \
  }

  // ---------- main loop: steps 1..126 in pairs, then 127 ----------
  #pragma unroll 1
  for (int tt = 1; tt <= 125; tt += 2) {
    STEP(tt, 1, 0)
    STEP(tt + 1, 0, 1)
  }
  STEP(127, 1, 0)

#undef STEP
#undef MM8

  // ---------- epilogue ----------
  {
    const float* st0 = &sST[1][ml][0];
    const float* st1 = &sST[1][16 + ml][0];
    f32x4 u0 = *(const f32x4*)(st0);
    f32x4 u1 = *(const f32x4*)(st0 + 4);
    f32x4 v0 = *(const f32x4*)(st1);
    f32x4 v1 = *(const f32x4*)(st1 + 4);
    float s1a = (u0[0] + u0[2]) + (u1[0] + u1[2]);
    float s2a = (u0[1] + u0[3]) + (u1[1] + u1[3]);
    float s1b = (v0[0] + v0[2]) + (v1[0] + v1[2]);
    float s2b = (v0[1] + v0[3]) + (v1[1] + v1[3]);
    float rs_f[2], nrsmu[2];
    {
      float mua = s1a * (1.f / 256.f);
      float vea = fmaf(s2a, 1.f / 256.f, -mua * mua) + 1e-5f;
      rs_f[0] = __frsqrt_rn(vea); nrsmu[0] = -rs_f[0] * mua;
      float mub = s1b * (1.f / 256.f);
      float veb = fmaf(s2b, 1.f / 256.f, -mub * mub) + 1e-5f;
      rs_f[1] = __frsqrt_rn(veb); nrsmu[1] = -rs_f[1] * mub;
    }
    // sOW over sD1 (dd reads all done before last barrier)
    f16* sOW = (f16*)sD1;
    for (int idx = tid; idx < 512; idx += 256) {
      int c = idx >> 6, l2 = idx & 63, q2 = l2 >> 4, o = l2 & 15;
      int k0 = c * 32 + q2 * 4;
      f16x8 f;
      #pragma unroll
      for (int j = 0; j < 8; j++) f[j] = (f16)0.f;
      if (o < OUTD) {
        const float* orow = out_w + o * HDIM;
        float4 a0 = *(const float4*)(orow + k0);
        float4 a1 = *(const float4*)(orow + k0 + 16);
        float4 g0 = *(const float4*)(gamma + k0);
        float4 g1 = *(const float4*)(gamma + k0 + 16);
        f[0]=(f16)(g0.x*a0.x); f[1]=(f16)(g0.y*a0.y); f[2]=(f16)(g0.z*a0.z); f[3]=(f16)(g0.w*a0.w);
        f[4]=(f16)(g1.x*a1.x); f[5]=(f16)(g1.y*a1.y); f[6]=(f16)(g1.z*a1.z); f[7]=(f16)(g1.w*a1.w);
      }
      *(f16x8*)(sOW + idx * 8) = f;
    }
    __syncthreads();
    float* sOut = (float*)&sFR[0][0][0][0][0];  // [2][4][16][16] floats (8 KB, != sFR[1])
    #pragma unroll
    for (int g = 0; g < 2; g++) {
      f32x4 aO = {0.f, 0.f, 0.f, 0.f};
      #pragma unroll
      for (int cp = 0; cp < 2; cp++) {
        f16x8 fr = *(const f16x8*)&sFR[1][g][2 * w + cp][l][0];
        f16x8 af;
        #pragma unroll
        for (int j = 0; j < 8; j++)
          af[j] = (f16)fmaf(rs_f[g], (float)fr[j], nrsmu[g]);
        f16x8 of = *(const f16x8*)(sOW + ((size_t)(2 * w + cp) * 64 + l) * 8);
        aO = __builtin_amdgcn_mfma_f32_16x16x32_f16(of, af, aO, 0, 0, 0);
      }
      #pragma unroll
      for (int r = 0; r < 4; r++)
        sOut[((g * 4 + w) * 16 + ml) * 16 + q * 4 + r] = aO[r];
    }
    __syncthreads();
    for (int idx = tid; idx < 32 * OUTD; idx += 256) {
      int m = idx / OUTD, o = idx - m * OUTD;
      int g = m >> 4, mm = m & 15;
      float s = 0.f;
      #pragma unroll
      for (int ww = 0; ww < 4; ww++) s += sOut[((g * 4 + ww) * 16 + mm) * 16 + o];
      out[(size_t)(base + m) * OUTD + o] = s + sOB[o];
    }
  }
}

extern "C" void kernel_launch(void* const* d_in, const int* in_sizes, int n_in,
                              void* d_out, int out_size, void* d_ws, size_t ws_size,
                              hipStream_t stream) {
  const float* x   = (const float*)d_in[0];
  const float* ew  = (const float*)d_in[1];
  const float* eb  = (const float*)d_in[2];
  const float* uw  = (const float*)d_in[3];
  const float* ub  = (const float*)d_in[4];
  const float* g   = (const float*)d_in[5];
  const float* be  = (const float*)d_in[6];
  const float* ow  = (const float*)d_in[7];
  const float* ob  = (const float*)d_in[8];
  float* out = (float*)d_out;

  const int B = in_sizes[0] / TST;      // 16384
  const int grid = B / 32;              // 512 blocks = 2/CU, ONE round
  hipLaunchKernelGGL(rnn_kernel, dim3(grid), dim3(256), 0, stream,
                     x, ew, eb, uw, ub, g, be, ow, ob, out);
}

// Round 8
// 359.335 us; speedup vs baseline: 1.0737x; 1.0737x over previous
//
#include <hip/hip_runtime.h>
#include <hip/hip_fp16.h>
#include <math.h>

typedef _Float16 f16;
typedef _Float16 f16x2 __attribute__((ext_vector_type(2)));
typedef _Float16 f16x8 __attribute__((ext_vector_type(8)));
typedef float f32x4 __attribute__((ext_vector_type(4)));
typedef unsigned char u8;

#define HDIM 256
#define TST 128
#define OUTD 10
#define S2LE 2.8853900817779268f   // 2*log2(e)

static __device__ __forceinline__ f16x2 pkrtz(float a, float b) {
  auto r = __builtin_amdgcn_cvt_pkrtz(a, b);
  return *(f16x2*)&r;
}

// Double-pumped R5 geometry: 4 waves/block, wave owns 64 hidden rows; block
// owns 32 batch cols as 2 groups of 16, processed HALF A STEP out of phase:
//   P1(t):   MFMA(g1,t)   || elementwise(g0,t)    -> barrier
//   P0(t+1): MFMA(g0,t+1) || elementwise(g1,t)    -> barrier
// acc crosses barriers in registers; frag buffers single (write->read always
// separated by exactly one barrier); stats double-buffered by step parity:
// elem(s) reads parity (s-1)&1, writes parity s&1.
// Algebra: y(t) = rs(t-1)*(Wg@tv(t-1)) + dd(xv_t) - rs(t-1)*mu(t-1)*RSg.
__global__ __launch_bounds__(256, 2) void rnn_kernel(
    const float* __restrict__ x,
    const float* __restrict__ embed_w,
    const float* __restrict__ embed_b,
    const float* __restrict__ update_w,
    const float* __restrict__ update_b,
    const float* __restrict__ gamma,
    const float* __restrict__ beta,
    const float* __restrict__ out_w,
    const float* __restrict__ out_b,
    float* __restrict__ out)
{
  __shared__ __align__(16) f16   sFR[2][8][64][8];   // [group][chunk][lane][8] 16 KB, single-buffered
  __shared__ __align__(16) float sD1[10 * 260];      // 10.4 KB; epi overlay: sOW
  __shared__ __align__(16) float sBW[HDIM];
  __shared__ __align__(16) float sRSg[HDIM];
  __shared__ __align__(16) float sST[2][2][16][12];  // [group][parity][col][8 used]
  __shared__ float sOB[16];
  __shared__ u8    sXb[TST][32];

  const int tid = threadIdx.x;
  const int w  = tid >> 6;      // 0..3
  const int l  = tid & 63;
  const int q  = l >> 4;
  const int ml = l & 15;
  const int base = blockIdx.x * 32;
  const int nb = w * 64 + q * 4;

  float* T0 = (float*)&sFR[0][0][0][0];   // [256][10] init-only overlay (10 KB < 16 KB)

  // ---------- P-init 1 ----------
  {
    float ew = embed_w[tid], eb = embed_b[tid];
    #pragma unroll
    for (int xv = 0; xv < 10; xv++)
      T0[tid * 10 + xv] = tanhf((float)xv * ew + eb);
  }
  for (int idx = tid; idx < 32 * TST; idx += 256) {
    int col = idx >> 7, tt = idx & 127;
    sXb[tt][col] = (u8)(int)x[(size_t)(base + col) * TST + tt];
  }
  if (tid < 16) {
    float v = 0.f;
    if (tid < OUTD) {
      v = out_b[tid];
      const float* orow = out_w + tid * HDIM;
      for (int k = 0; k < HDIM; k += 4) {
        float4 wv = *(const float4*)(orow + k);
        float4 bv = *(const float4*)(beta + k);
        v = fmaf(wv.x, bv.x, fmaf(wv.y, bv.y, fmaf(wv.z, bv.z, fmaf(wv.w, bv.w, v))));
      }
    }
    sOB[tid] = v;
  }
  __syncthreads();

  // ---------- P-init 2: per-n tables (n = tid) ----------
  {
    const int n = tid;
    const float* wrow = update_w + n * HDIM;
    float ty[10];
    #pragma unroll
    for (int xv = 0; xv < 10; xv++) ty[xv] = 0.f;
    float bw = 0.f, rsg = 0.f;
    for (int k = 0; k < HDIM; k += 4) {
      float4 wv4 = *(const float4*)(wrow + k);
      float4 b4  = *(const float4*)(beta + k);
      float4 g4  = *(const float4*)(gamma + k);
      bw  = fmaf(wv4.x, b4.x, fmaf(wv4.y, b4.y, fmaf(wv4.z, b4.z, fmaf(wv4.w, b4.w, bw))));
      rsg = fmaf(wv4.x, S2LE * g4.x, fmaf(wv4.y, S2LE * g4.y,
            fmaf(wv4.z, S2LE * g4.z, fmaf(wv4.w, S2LE * g4.w, rsg))));
      #pragma unroll
      for (int kk = 0; kk < 4; kk++) {
        float wv = ((const float*)&wv4)[kk];
        const float* t0r = T0 + (k + kk) * 10;
        #pragma unroll
        for (int xv = 0; xv < 10; xv++) ty[xv] = fmaf(wv, t0r[xv], ty[xv]);
      }
    }
    float ubn = update_b[n];
    sBW[n]  = S2LE * bw;
    sRSg[n] = rsg;
    #pragma unroll
    for (int xv = 0; xv < 10; xv++)
      sD1[xv * 260 + n] = S2LE * (ty[xv] + ubn + bw);
  }
  __syncthreads();

  // ---------- W_g fragments (128 regs) ----------
  f16x8 wf[4][8];
  #pragma unroll
  for (int c = 0; c < 8; c++) {
    const int k0 = c * 32 + q * 4;
    float4 g0 = *(const float4*)(gamma + k0);
    float4 g1 = *(const float4*)(gamma + k0 + 16);
    #pragma unroll
    for (int nt = 0; nt < 4; nt++) {
      const float* wrow = update_w + (w * 64 + nt * 16 + ml) * HDIM;
      float4 a0 = *(const float4*)(wrow + k0);
      float4 a1 = *(const float4*)(wrow + k0 + 16);
      f16x8 f;
      f[0]=(f16)(S2LE*g0.x*a0.x); f[1]=(f16)(S2LE*g0.y*a0.y);
      f[2]=(f16)(S2LE*g0.z*a0.z); f[3]=(f16)(S2LE*g0.w*a0.w);
      f[4]=(f16)(S2LE*g1.x*a1.x); f[5]=(f16)(S2LE*g1.y*a1.y);
      f[6]=(f16)(S2LE*g1.z*a1.z); f[7]=(f16)(S2LE*g1.w*a1.w);
      wf[nt][c] = f;
    }
  }
  f32x4 rsgr[4];
  #pragma unroll
  for (int nt = 0; nt < 4; nt++)
    rsgr[nt] = *(const f32x4*)(sRSg + nb + nt * 16);

  f32x4 acc0[4], acc1[4];

  // ---------- prologue t=0: tv(0) both groups ----------
  {
    #pragma unroll
    for (int g = 0; g < 2; g++) {
      const int xv0 = (int)sXb[0][g * 16 + ml];
      const float* dp = sD1 + xv0 * 260;
      float p1 = 0.f, p2 = 0.f;
      #pragma unroll
      for (int cp = 0; cp < 2; cp++) {
        union { f16x8 v8; f16x2 v2[4]; } pk;
        #pragma unroll
        for (int h = 0; h < 2; h++) {
          const int nt = 2 * cp + h;
          f32x4 dd = *(const f32x4*)(dp + nb + nt * 16);
          f32x4 bw = *(const f32x4*)(sBW + nb + nt * 16);
          float tq[4];
          #pragma unroll
          for (int r = 0; r < 4; r++) {
            float y = dd[r] - bw[r];
            float e = __builtin_amdgcn_exp2f(y);
            float tv = fmaf(-2.f, __builtin_amdgcn_rcpf(e + 1.f), 1.f);
            tq[r] = tv; p1 += tv; p2 = fmaf(tv, tv, p2);
          }
          pk.v2[2 * h]     = pkrtz(tq[0], tq[1]);
          pk.v2[2 * h + 1] = pkrtz(tq[2], tq[3]);
        }
        *(f16x8*)&sFR[g][2 * w + cp][l][0] = pk.v8;
      }
      p1 += __shfl_xor(p1, 16, 64); p2 += __shfl_xor(p2, 16, 64);
      p1 += __shfl_xor(p1, 32, 64); p2 += __shfl_xor(p2, 32, 64);
      if (l < 16) *(float2*)&sST[g][0][ml][2 * w] = make_float2(p1, p2);
    }
    __syncthreads();
  }

#define MMG(FB, CC, CUR, NXT, ACC)                                             \
    { if ((CC) < 7) NXT = *(const f16x8*)((FB) + ((CC) + 1) * 512 + l * 8);    \
      ACC[0] = __builtin_amdgcn_mfma_f32_16x16x32_f16(wf[0][CC], CUR, ACC[0],0,0,0); \
      ACC[1] = __builtin_amdgcn_mfma_f32_16x16x32_f16(wf[1][CC], CUR, ACC[1],0,0,0); \
      ACC[2] = __builtin_amdgcn_mfma_f32_16x16x32_f16(wf[2][CC], CUR, ACC[2],0,0,0); \
      ACC[3] = __builtin_amdgcn_mfma_f32_16x16x32_f16(wf[3][CC], CUR, ACC[3],0,0,0); }

#define SLICE(S, ACCE)                                                         \
    { _Pragma("unroll") for (int r_ = 0; r_ < 4; r_++) {                       \
        float y_ = fmaf(rs_, ACCE[S][r_], fmaf(-rm_, rsgr[S][r_], dd_[S][r_]));\
        float e_ = __builtin_amdgcn_exp2f(y_);                                 \
        float v_ = fmaf(-2.f, __builtin_amdgcn_rcpf(e_ + 1.f), 1.f);           \
        tv_[S][r_] = v_; p1_ += v_; p2_ = fmaf(v_, v_, p2_); } }

// PHASE(TE,...): MFMA group GM (frags sFR[GM] -> ACCM) || elementwise group GE
// (step TE) consuming ACCE; stats read sST[GE][RP], write sST[GE][WP];
// pack -> sFR[GE]. One barrier at end.
#define PHASE(TE, GM, GE, RP, WP, ACCM, ACCE, XOFF)                            \
  {                                                                            \
    const float* st_ = &sST[GE][RP][ml][0];                                    \
    f32x4 u0_ = *(const f32x4*)(st_);                                          \
    f32x4 u1_ = *(const f32x4*)(st_ + 4);                                      \
    const int xv_ = (int)sXb[TE][XOFF + ml];                                   \
    const float* dp_ = sD1 + xv_ * 260 + nb;                                   \
    f32x4 dd_[4];                                                              \
    _Pragma("unroll") for (int n_ = 0; n_ < 4; n_++)                           \
      dd_[n_] = *(const f32x4*)(dp_ + n_ * 16);                                \
    const f16* fbm_ = &sFR[GM][0][0][0];                                       \
    f16x8 rA_ = *(const f16x8*)(fbm_ + l * 8);                                 \
    f16x8 rB_;                                                                 \
    _Pragma("unroll") for (int n_ = 0; n_ < 4; n_++)                           \
      ACCM[n_] = (f32x4){0.f, 0.f, 0.f, 0.f};                                  \
    f32x4 tv_[4];                                                              \
    float p1_ = 0.f, p2_ = 0.f;                                                \
    MMG(fbm_, 0, rA_, rB_, ACCM)                                               \
    MMG(fbm_, 1, rB_, rA_, ACCM)                                               \
    float s1_ = (u0_[0] + u0_[2]) + (u1_[0] + u1_[2]);                         \
    float s2_ = (u0_[1] + u0_[3]) + (u1_[1] + u1_[3]);                         \
    float mu_ = s1_ * (1.f / 256.f);                                           \
    float rs_ = __frsqrt_rn(fmaf(s2_, 1.f / 256.f, -mu_ * mu_) + 1e-5f);       \
    float rm_ = rs_ * mu_;                                                     \
    SLICE(0, ACCE)                                                             \
    MMG(fbm_, 2, rA_, rB_, ACCM)                                               \
    MMG(fbm_, 3, rB_, rA_, ACCM)                                               \
    SLICE(1, ACCE)                                                             \
    MMG(fbm_, 4, rA_, rB_, ACCM)                                               \
    MMG(fbm_, 5, rB_, rA_, ACCM)                                               \
    SLICE(2, ACCE)                                                             \
    MMG(fbm_, 6, rA_, rB_, ACCM)                                               \
    MMG(fbm_, 7, rB_, rA_, ACCM)                                               \
    SLICE(3, ACCE)                                                             \
    _Pragma("unroll") for (int cp_ = 0; cp_ < 2; cp_++) {                      \
      union { f16x8 v8; f16x2 v2[4]; } k_;                                     \
      k_.v2[0] = pkrtz(tv_[2 * cp_][0], tv_[2 * cp_][1]);                      \
      k_.v2[1] = pkrtz(tv_[2 * cp_][2], tv_[2 * cp_][3]);                      \
      k_.v2[2] = pkrtz(tv_[2 * cp_ + 1][0], tv_[2 * cp_ + 1][1]);              \
      k_.v2[3] = pkrtz(tv_[2 * cp_ + 1][2], tv_[2 * cp_ + 1][3]);              \
      *(f16x8*)&sFR[GE][2 * w + cp_][l][0] = k_.v8;                            \
    }                                                                          \
    p1_ += __shfl_xor(p1_, 16, 64); p2_ += __shfl_xor(p2_, 16, 64);            \
    p1_ += __shfl_xor(p1_, 32, 64); p2_ += __shfl_xor(p2_, 32, 64);            \
    if (l < 16) *(float2*)&sST[GE][WP][ml][2 * w] = make_float2(p1_, p2_);     \
    __syncthreads();                                                           \
  }

  // ---------- P0(1): MFMA g0 only ----------
  {
    const f16* fbm_ = &sFR[0][0][0][0];
    f16x8 rA_ = *(const f16x8*)(fbm_ + l * 8);
    f16x8 rB_;
    #pragma unroll
    for (int n_ = 0; n_ < 4; n_++) acc0[n_] = (f32x4){0.f, 0.f, 0.f, 0.f};
    MMG(fbm_, 0, rA_, rB_, acc0)
    MMG(fbm_, 1, rB_, rA_, acc0)
    MMG(fbm_, 2, rA_, rB_, acc0)
    MMG(fbm_, 3, rB_, rA_, acc0)
    MMG(fbm_, 4, rA_, rB_, acc0)
    MMG(fbm_, 5, rB_, rA_, acc0)
    MMG(fbm_, 6, rA_, rB_, acc0)
    MMG(fbm_, 7, rB_, rA_, acc0)
    __syncthreads();
  }

  // ---------- main loop ----------
  // elem(s) reads stats parity (s-1)&1, writes parity s&1.  t is odd:
  //   P1(t):   elem g0(t):   RP=0 WP=1
  //   P0(t+1): elem g1(t):   RP=0 WP=1
  //   P1(t+1): elem g0(t+1): RP=1 WP=0
  //   P0(t+2): elem g1(t+1): RP=1 WP=0
  #pragma unroll 1
  for (int t = 1; t <= 125; t += 2) {
    PHASE(t,     1, 0, 0, 1, acc1, acc0, 0)
    PHASE(t,     0, 1, 0, 1, acc0, acc1, 16)
    PHASE(t + 1, 1, 0, 1, 0, acc1, acc0, 0)
    PHASE(t + 1, 0, 1, 1, 0, acc0, acc1, 16)
  }
  PHASE(127, 1, 0, 0, 1, acc1, acc0, 0)        // P1(127): elem g0(127) r0 w1

  // ---------- epilogue ----------
  {
    // elementwise g1(127): stats g1(126) parity 0 -> sST[1][0]
    const float* st_ = &sST[1][0][ml][0];
    f32x4 u0_ = *(const f32x4*)(st_);
    f32x4 u1_ = *(const f32x4*)(st_ + 4);
    float s1_ = (u0_[0] + u0_[2]) + (u1_[0] + u1_[2]);
    float s2_ = (u0_[1] + u0_[3]) + (u1_[1] + u1_[3]);
    float mu_ = s1_ * (1.f / 256.f);
    float rs_ = __frsqrt_rn(fmaf(s2_, 1.f / 256.f, -mu_ * mu_) + 1e-5f);
    float rm_ = rs_ * mu_;
    const int xv_ = (int)sXb[127][16 + ml];
    const float* dp_ = sD1 + xv_ * 260 + nb;
    f32x4 tvb[4];
    float p1_ = 0.f, p2_ = 0.f;
    #pragma unroll
    for (int nt = 0; nt < 4; nt++) {
      f32x4 dd = *(const f32x4*)(dp_ + nt * 16);
      #pragma unroll
      for (int r = 0; r < 4; r++) {
        float y = fmaf(rs_, acc1[nt][r], fmaf(-rm_, rsgr[nt][r], dd[r]));
        float e = __builtin_amdgcn_exp2f(y);
        float v = fmaf(-2.f, __builtin_amdgcn_rcpf(e + 1.f), 1.f);
        tvb[nt][r] = v; p1_ += v; p2_ = fmaf(v, v, p2_);
      }
    }
    p1_ += __shfl_xor(p1_, 16, 64); p2_ += __shfl_xor(p2_, 16, 64);
    p1_ += __shfl_xor(p1_, 32, 64); p2_ += __shfl_xor(p2_, 32, 64);
    if (l < 16) *(float2*)&sST[1][1][ml][2 * w] = make_float2(p1_, p2_);
    __syncthreads();

    // build sOW over sD1 (all dd reads done before the barrier above)
    f16* sOW = (f16*)sD1;
    for (int idx = tid; idx < 512; idx += 256) {
      int c = idx >> 6, l2 = idx & 63, q2 = l2 >> 4, o = l2 & 15;
      int k0 = c * 32 + q2 * 4;
      f16x8 f;
      #pragma unroll
      for (int j = 0; j < 8; j++) f[j] = (f16)0.f;
      if (o < OUTD) {
        const float* orow = out_w + o * HDIM;
        float4 a0 = *(const float4*)(orow + k0);
        float4 a1 = *(const float4*)(orow + k0 + 16);
        float4 g0 = *(const float4*)(gamma + k0);
        float4 g1 = *(const float4*)(gamma + k0 + 16);
        f[0]=(f16)(g0.x*a0.x); f[1]=(f16)(g0.y*a0.y); f[2]=(f16)(g0.z*a0.z); f[3]=(f16)(g0.w*a0.w);
        f[4]=(f16)(g1.x*a1.x); f[5]=(f16)(g1.y*a1.y); f[6]=(f16)(g1.z*a1.z); f[7]=(f16)(g1.w*a1.w);
      }
      *(f16x8*)(sOW + idx * 8) = f;
    }
    // final stats: g0(127) -> sST[0][1] (from PHASE(127)); g1(127) -> sST[1][1]
    float rs_f[2], nrsmu[2];
    #pragma unroll
    for (int g = 0; g < 2; g++) {
      const float* st = &sST[g][1][ml][0];
      f32x4 a0 = *(const f32x4*)(st);
      f32x4 a1 = *(const f32x4*)(st + 4);
      float s1 = (a0[0] + a0[2]) + (a1[0] + a1[2]);
      float s2 = (a0[1] + a0[3]) + (a1[1] + a1[3]);
      float mu = s1 * (1.f / 256.f);
      float ve = fmaf(s2, 1.f / 256.f, -mu * mu) + 1e-5f;
      rs_f[g] = __frsqrt_rn(ve); nrsmu[g] = -rs_f[g] * mu;
    }
    __syncthreads();

    float* sOut = (float*)&sFR[1][0][0][0];  // 8 KB overlay on g1 frags (unused now)
    // g0 from LDS frags (tv_g0(127) written by PHASE(127))
    {
      f32x4 aO = {0.f, 0.f, 0.f, 0.f};
      #pragma unroll
      for (int cp = 0; cp < 2; cp++) {
        f16x8 fr = *(const f16x8*)&sFR[0][2 * w + cp][l][0];
        f16x8 af;
        #pragma unroll
        for (int j = 0; j < 8; j++)
          af[j] = (f16)fmaf(rs_f[0], (float)fr[j], nrsmu[0]);
        f16x8 of = *(const f16x8*)(sOW + ((size_t)(2 * w + cp) * 64 + l) * 8);
        aO = __builtin_amdgcn_mfma_f32_16x16x32_f16(of, af, aO, 0, 0, 0);
      }
      #pragma unroll
      for (int r = 0; r < 4; r++)
        sOut[((0 * 4 + w) * 16 + ml) * 16 + q * 4 + r] = aO[r];
    }
    // g1 from regs (tvb)
    {
      f32x4 aO = {0.f, 0.f, 0.f, 0.f};
      #pragma unroll
      for (int cp = 0; cp < 2; cp++) {
        f16x8 af;
        #pragma unroll
        for (int j = 0; j < 8; j++)
          af[j] = (f16)fmaf(rs_f[1], tvb[2 * cp + (j >> 2)][j & 3], nrsmu[1]);
        f16x8 of = *(const f16x8*)(sOW + ((size_t)(2 * w + cp) * 64 + l) * 8);
        aO = __builtin_amdgcn_mfma_f32_16x16x32_f16(of, af, aO, 0, 0, 0);
      }
      #pragma unroll
      for (int r = 0; r < 4; r++)
        sOut[((1 * 4 + w) * 16 + ml) * 16 + q * 4 + r] = aO[r];
    }
    __syncthreads();
    for (int idx = tid; idx < 32 * OUTD; idx += 256) {
      int m = idx / OUTD, o = idx - m * OUTD;
      int g = m >> 4, mm = m & 15;
      float s = 0.f;
      #pragma unroll
      for (int ww = 0; ww < 4; ww++) s += sOut[((g * 4 + ww) * 16 + mm) * 16 + o];
      out[(size_t)(base + m) * OUTD + o] = s + sOB[o];
    }
  }
}

extern "C" void kernel_launch(void* const* d_in, const int* in_sizes, int n_in,
                              void* d_out, int out_size, void* d_ws, size_t ws_size,
                              hipStream_t stream) {
  const float* x   = (const float*)d_in[0];
  const float* ew  = (const float*)d_in[1];
  const float* eb  = (const float*)d_in[2];
  const float* uw  = (const float*)d_in[3];
  const float* ub  = (const float*)d_in[4];
  const float* g   = (const float*)d_in[5];
  const float* be  = (const float*)d_in[6];
  const float* ow  = (const float*)d_in[7];
  const float* ob  = (const float*)d_in[8];
  float* out = (float*)d_out;

  const int B = in_sizes[0] / TST;      // 16384
  const int grid = B / 32;              // 512 blocks = 2/CU, one round
  hipLaunchKernelGGL(rnn_kernel, dim3(grid), dim3(256), 0, stream,
                     x, ew, eb, uw, ub, g, be, ow, ob, out);
}

// Round 9
// 353.880 us; speedup vs baseline: 1.0903x; 1.0154x over previous
//
#include <hip/hip_runtime.h>
#include <hip/hip_fp16.h>
#include <math.h>

typedef _Float16 f16;
typedef _Float16 f16x2 __attribute__((ext_vector_type(2)));
typedef _Float16 f16x8 __attribute__((ext_vector_type(8)));
typedef float f32x4 __attribute__((ext_vector_type(4)));
typedef unsigned char u8;

#define HDIM 256
#define TST 128
#define OUTD 10
#define S2LE 2.8853900817779268f   // 2*log2(e)

static __device__ __forceinline__ f16x2 pkrtz(float a, float b) {
  auto r = __builtin_amdgcn_cvt_pkrtz(a, b);
  return *(f16x2*)&r;
}

// R8 double-pump + MFMA-resident LN stats:
//   In the phase that loads group G's frags (all 256 k per column),
//   Gram = mfma(frag,frag,·)  -> diag = S2[col];  mfma(ones,frag,·) -> S1[col].
//   Stats hand off wave-locally in registers (S1O/S2O -> next phase's S1E/S2E);
//   sST / shfl_xor / parity machinery deleted.
__global__ __launch_bounds__(256, 2) void rnn_kernel(
    const float* __restrict__ x,
    const float* __restrict__ embed_w,
    const float* __restrict__ embed_b,
    const float* __restrict__ update_w,
    const float* __restrict__ update_b,
    const float* __restrict__ gamma,
    const float* __restrict__ beta,
    const float* __restrict__ out_w,
    const float* __restrict__ out_b,
    float* __restrict__ out)
{
  __shared__ __align__(16) f16   sFR[2][8][64][8];   // 16 KB; overlays: T0 (init), sOut (epi)
  __shared__ __align__(16) float sD1[10 * 260];      // 10.4 KB; epi overlay: sOW
  __shared__ __align__(16) float sBW[HDIM];
  __shared__ __align__(16) float sRSg[HDIM];
  __shared__ float sOB[16];
  __shared__ u8    sXb[TST][32];

  const int tid = threadIdx.x;
  const int w  = tid >> 6;      // 0..3
  const int l  = tid & 63;
  const int q  = l >> 4;
  const int ml = l & 15;
  const int base = blockIdx.x * 32;
  const int nb = w * 64 + q * 4;
  const int m3 = ml & 3;
  const int srcl = ((ml >> 2) << 4) + ml;   // lane holding Gram diag for column ml

  float* T0 = (float*)&sFR[0][0][0][0];   // [256][10] init-only overlay

  // ---------- P-init 1 ----------
  {
    float ew = embed_w[tid], eb = embed_b[tid];
    #pragma unroll
    for (int xv = 0; xv < 10; xv++)
      T0[tid * 10 + xv] = tanhf((float)xv * ew + eb);
  }
  for (int idx = tid; idx < 32 * TST; idx += 256) {
    int col = idx >> 7, tt = idx & 127;
    sXb[tt][col] = (u8)(int)x[(size_t)(base + col) * TST + tt];
  }
  if (tid < 16) {
    float v = 0.f;
    if (tid < OUTD) {
      v = out_b[tid];
      const float* orow = out_w + tid * HDIM;
      for (int k = 0; k < HDIM; k += 4) {
        float4 wv = *(const float4*)(orow + k);
        float4 bv = *(const float4*)(beta + k);
        v = fmaf(wv.x, bv.x, fmaf(wv.y, bv.y, fmaf(wv.z, bv.z, fmaf(wv.w, bv.w, v))));
      }
    }
    sOB[tid] = v;
  }
  __syncthreads();

  // ---------- P-init 2: per-n tables (n = tid) ----------
  {
    const int n = tid;
    const float* wrow = update_w + n * HDIM;
    float ty[10];
    #pragma unroll
    for (int xv = 0; xv < 10; xv++) ty[xv] = 0.f;
    float bw = 0.f, rsg = 0.f;
    for (int k = 0; k < HDIM; k += 4) {
      float4 wv4 = *(const float4*)(wrow + k);
      float4 b4  = *(const float4*)(beta + k);
      float4 g4  = *(const float4*)(gamma + k);
      bw  = fmaf(wv4.x, b4.x, fmaf(wv4.y, b4.y, fmaf(wv4.z, b4.z, fmaf(wv4.w, b4.w, bw))));
      rsg = fmaf(wv4.x, S2LE * g4.x, fmaf(wv4.y, S2LE * g4.y,
            fmaf(wv4.z, S2LE * g4.z, fmaf(wv4.w, S2LE * g4.w, rsg))));
      #pragma unroll
      for (int kk = 0; kk < 4; kk++) {
        float wv = ((const float*)&wv4)[kk];
        const float* t0r = T0 + (k + kk) * 10;
        #pragma unroll
        for (int xv = 0; xv < 10; xv++) ty[xv] = fmaf(wv, t0r[xv], ty[xv]);
      }
    }
    float ubn = update_b[n];
    sBW[n]  = S2LE * bw;
    sRSg[n] = rsg;
    #pragma unroll
    for (int xv = 0; xv < 10; xv++)
      sD1[xv * 260 + n] = S2LE * (ty[xv] + ubn + bw);
  }
  __syncthreads();

  // ---------- W_g fragments (128 regs) ----------
  f16x8 wf[4][8];
  #pragma unroll
  for (int c = 0; c < 8; c++) {
    const int k0 = c * 32 + q * 4;
    float4 g0 = *(const float4*)(gamma + k0);
    float4 g1 = *(const float4*)(gamma + k0 + 16);
    #pragma unroll
    for (int nt = 0; nt < 4; nt++) {
      const float* wrow = update_w + (w * 64 + nt * 16 + ml) * HDIM;
      float4 a0 = *(const float4*)(wrow + k0);
      float4 a1 = *(const float4*)(wrow + k0 + 16);
      f16x8 f;
      f[0]=(f16)(S2LE*g0.x*a0.x); f[1]=(f16)(S2LE*g0.y*a0.y);
      f[2]=(f16)(S2LE*g0.z*a0.z); f[3]=(f16)(S2LE*g0.w*a0.w);
      f[4]=(f16)(S2LE*g1.x*a1.x); f[5]=(f16)(S2LE*g1.y*a1.y);
      f[6]=(f16)(S2LE*g1.z*a1.z); f[7]=(f16)(S2LE*g1.w*a1.w);
      wf[nt][c] = f;
    }
  }
  f32x4 rsgr[4];
  #pragma unroll
  for (int nt = 0; nt < 4; nt++)
    rsgr[nt] = *(const f32x4*)(sRSg + nb + nt * 16);

  f16x8 ones_;
  #pragma unroll
  for (int j = 0; j < 8; j++) ones_[j] = (f16)1.f;

  f32x4 acc0[4], acc1[4];
  float s1A = 0.f, s2A = 0.f, s1B = 0.f, s2B = 0.f;

  // ---------- prologue t=0: tv(0) both groups -> frags (no stats) ----------
  {
    #pragma unroll
    for (int g = 0; g < 2; g++) {
      const int xv0 = (int)sXb[0][g * 16 + ml];
      const float* dp = sD1 + xv0 * 260;
      #pragma unroll
      for (int cp = 0; cp < 2; cp++) {
        union { f16x8 v8; f16x2 v2[4]; } pk;
        #pragma unroll
        for (int h = 0; h < 2; h++) {
          const int nt = 2 * cp + h;
          f32x4 dd = *(const f32x4*)(dp + nb + nt * 16);
          f32x4 bw = *(const f32x4*)(sBW + nb + nt * 16);
          float tq[4];
          #pragma unroll
          for (int r = 0; r < 4; r++) {
            float y = dd[r] - bw[r];
            float e = __builtin_amdgcn_exp2f(y);
            float tv = fmaf(-2.f, __builtin_amdgcn_rcpf(e + 1.f), 1.f);
            tq[r] = tv;
          }
          pk.v2[2 * h]     = pkrtz(tq[0], tq[1]);
          pk.v2[2 * h + 1] = pkrtz(tq[2], tq[3]);
        }
        *(f16x8*)&sFR[g][2 * w + cp][l][0] = pk.v8;
      }
    }
    __syncthreads();
  }

#define MMG3(FB, CC, CUR, NXT, ACC, AG, AS)                                    \
    { if ((CC) < 7) NXT = *(const f16x8*)((FB) + ((CC) + 1) * 512 + l * 8);    \
      ACC[0] = __builtin_amdgcn_mfma_f32_16x16x32_f16(wf[0][CC], CUR, ACC[0],0,0,0); \
      ACC[1] = __builtin_amdgcn_mfma_f32_16x16x32_f16(wf[1][CC], CUR, ACC[1],0,0,0); \
      ACC[2] = __builtin_amdgcn_mfma_f32_16x16x32_f16(wf[2][CC], CUR, ACC[2],0,0,0); \
      ACC[3] = __builtin_amdgcn_mfma_f32_16x16x32_f16(wf[3][CC], CUR, ACC[3],0,0,0); \
      AG = __builtin_amdgcn_mfma_f32_16x16x32_f16(CUR, CUR, AG, 0, 0, 0);      \
      AS = __builtin_amdgcn_mfma_f32_16x16x32_f16(ones_, CUR, AS, 0, 0, 0); }

#define SLICE(S, ACCE)                                                         \
    { _Pragma("unroll") for (int r_ = 0; r_ < 4; r_++) {                       \
        float y_ = fmaf(rs_, ACCE[S][r_], fmaf(-rm_, rsgr[S][r_], dd_[S][r_]));\
        float e_ = __builtin_amdgcn_exp2f(y_);                                 \
        tv_[S][r_] = fmaf(-2.f, __builtin_amdgcn_rcpf(e_ + 1.f), 1.f); } }

#define PACK(GE, CP)                                                           \
    { union { f16x8 v8; f16x2 v2[4]; } k_;                                     \
      k_.v2[0] = pkrtz(tv_[2*(CP)][0],   tv_[2*(CP)][1]);                      \
      k_.v2[1] = pkrtz(tv_[2*(CP)][2],   tv_[2*(CP)][3]);                      \
      k_.v2[2] = pkrtz(tv_[2*(CP)+1][0], tv_[2*(CP)+1][1]);                    \
      k_.v2[3] = pkrtz(tv_[2*(CP)+1][2], tv_[2*(CP)+1][3]);                    \
      *(f16x8*)&sFR[GE][2 * w + (CP)][l][0] = k_.v8; }

// PHASE: MFMA group GM (-> ACCM) + Gram/Ones stats of GM's loaded frags
// (-> S1O/S2O, extracted after the barrier), || elementwise group GE step TE
// consuming ACCE and stats S1E/S2E (register handoff from previous phase).
#define PHASE(TE, GM, GE, XOFF, ACCM, ACCE, S1E, S2E, S1O, S2O)                \
  {                                                                            \
    const int xv_ = (int)sXb[TE][XOFF + ml];                                   \
    const float* dp_ = sD1 + xv_ * 260 + nb;                                   \
    f32x4 dd_[4];                                                              \
    _Pragma("unroll") for (int n_ = 0; n_ < 4; n_++)                           \
      dd_[n_] = *(const f32x4*)(dp_ + n_ * 16);                                \
    const f16* fbm_ = &sFR[GM][0][0][0];                                       \
    f16x8 rA_ = *(const f16x8*)(fbm_ + l * 8);                                 \
    f16x8 rB_;                                                                 \
    f32x4 aG_ = {0.f,0.f,0.f,0.f}, aS_ = {0.f,0.f,0.f,0.f};                    \
    _Pragma("unroll") for (int n_ = 0; n_ < 4; n_++)                           \
      ACCM[n_] = (f32x4){0.f, 0.f, 0.f, 0.f};                                  \
    f32x4 tv_[4];                                                              \
    __builtin_amdgcn_s_setprio(1);                                             \
    MMG3(fbm_, 0, rA_, rB_, ACCM, aG_, aS_)                                    \
    MMG3(fbm_, 1, rB_, rA_, ACCM, aG_, aS_)                                    \
    float mu_ = (S1E) * (1.f / 256.f);                                         \
    float rs_ = __frsqrt_rn(fmaf((S2E), 1.f / 256.f, -mu_ * mu_) + 1e-5f);     \
    float rm_ = rs_ * mu_;                                                     \
    SLICE(0, ACCE)                                                             \
    MMG3(fbm_, 2, rA_, rB_, ACCM, aG_, aS_)                                    \
    MMG3(fbm_, 3, rB_, rA_, ACCM, aG_, aS_)                                    \
    SLICE(1, ACCE)                                                             \
    PACK(GE, 0)                                                                \
    MMG3(fbm_, 4, rA_, rB_, ACCM, aG_, aS_)                                    \
    MMG3(fbm_, 5, rB_, rA_, ACCM, aG_, aS_)                                    \
    SLICE(2, ACCE)                                                             \
    MMG3(fbm_, 6, rA_, rB_, ACCM, aG_, aS_)                                    \
    MMG3(fbm_, 7, rB_, rA_, ACCM, aG_, aS_)                                    \
    SLICE(3, ACCE)                                                             \
    PACK(GE, 1)                                                                \
    __builtin_amdgcn_s_setprio(0);                                             \
    __syncthreads();                                                           \
    S1O = aS_[0];                                                              \
    float sel_ = aG_[0];                                                       \
    sel_ = (m3 == 1) ? aG_[1] : sel_;                                          \
    sel_ = (m3 == 2) ? aG_[2] : sel_;                                          \
    sel_ = (m3 == 3) ? aG_[3] : sel_;                                          \
    S2O = __shfl(sel_, srcl, 64);                                              \
  }

  // ---------- P0(1): MFMA g0 + Gram/Ones -> acc0, stats(g0,0) ----------
  {
    const f16* fbm_ = &sFR[0][0][0][0];
    f16x8 rA_ = *(const f16x8*)(fbm_ + l * 8);
    f16x8 rB_;
    f32x4 aG_ = {0.f,0.f,0.f,0.f}, aS_ = {0.f,0.f,0.f,0.f};
    #pragma unroll
    for (int n_ = 0; n_ < 4; n_++) acc0[n_] = (f32x4){0.f, 0.f, 0.f, 0.f};
    MMG3(fbm_, 0, rA_, rB_, acc0, aG_, aS_)
    MMG3(fbm_, 1, rB_, rA_, acc0, aG_, aS_)
    MMG3(fbm_, 2, rA_, rB_, acc0, aG_, aS_)
    MMG3(fbm_, 3, rB_, rA_, acc0, aG_, aS_)
    MMG3(fbm_, 4, rA_, rB_, acc0, aG_, aS_)
    MMG3(fbm_, 5, rB_, rA_, acc0, aG_, aS_)
    MMG3(fbm_, 6, rA_, rB_, acc0, aG_, aS_)
    MMG3(fbm_, 7, rB_, rA_, acc0, aG_, aS_)
    __syncthreads();
    s1A = aS_[0];
    float sel_ = aG_[0];
    sel_ = (m3 == 1) ? aG_[1] : sel_;
    sel_ = (m3 == 2) ? aG_[2] : sel_;
    sel_ = (m3 == 3) ? aG_[3] : sel_;
    s2A = __shfl(sel_, srcl, 64);
  }

  // ---------- main loop: uniform 2 phases per step ----------
  #pragma unroll 1
  for (int t = 1; t <= 127; t++) {
    PHASE(t, 1, 0, 0,  acc1, acc0, s1A, s2A, s1B, s2B)
    PHASE(t, 0, 1, 16, acc0, acc1, s1B, s2B, s1A, s2A)
  }
  // after loop: s1A/s2A = stats(g0,127); sFR[0]=tv(g0,127); sFR[1]=tv(g1,127)

  // ---------- epilogue ----------
  {
    // stats(g1,127): Gram-only pass on sFR[1]
    f32x4 aG2 = {0.f,0.f,0.f,0.f}, aS2 = {0.f,0.f,0.f,0.f};
    const f16* fb1 = &sFR[1][0][0][0];
    #pragma unroll
    for (int c = 0; c < 8; c++) {
      f16x8 rr = *(const f16x8*)(fb1 + c * 512 + l * 8);
      aG2 = __builtin_amdgcn_mfma_f32_16x16x32_f16(rr, rr, aG2, 0, 0, 0);
      aS2 = __builtin_amdgcn_mfma_f32_16x16x32_f16(ones_, rr, aS2, 0, 0, 0);
    }
    float s1C = aS2[0];
    float sel2 = aG2[0];
    sel2 = (m3 == 1) ? aG2[1] : sel2;
    sel2 = (m3 == 2) ? aG2[2] : sel2;
    sel2 = (m3 == 3) ? aG2[3] : sel2;
    float s2C = __shfl(sel2, srcl, 64);

    float rsF[2], nmF[2];
    {
      float mu = s1A * (1.f / 256.f);
      float ve = fmaf(s2A, 1.f / 256.f, -mu * mu) + 1e-5f;
      rsF[0] = __frsqrt_rn(ve); nmF[0] = -rsF[0] * mu;
      float mu1 = s1C * (1.f / 256.f);
      float ve1 = fmaf(s2C, 1.f / 256.f, -mu1 * mu1) + 1e-5f;
      rsF[1] = __frsqrt_rn(ve1); nmF[1] = -rsF[1] * mu1;
    }
    // read own frag inputs (both groups) before sOut overlays sFR[0]
    f16x8 fin[2][2];
    #pragma unroll
    for (int g = 0; g < 2; g++)
      #pragma unroll
      for (int cp = 0; cp < 2; cp++)
        fin[g][cp] = *(const f16x8*)&sFR[g][2 * w + cp][l][0];

    // build sOW (gamma-folded out_w frags) over sD1
    f16* sOW = (f16*)sD1;
    for (int idx = tid; idx < 512; idx += 256) {
      int c = idx >> 6, l2 = idx & 63, q2 = l2 >> 4, o = l2 & 15;
      int k0 = c * 32 + q2 * 4;
      f16x8 f;
      #pragma unroll
      for (int j = 0; j < 8; j++) f[j] = (f16)0.f;
      if (o < OUTD) {
        const float* orow = out_w + o * HDIM;
        float4 a0 = *(const float4*)(orow + k0);
        float4 a1 = *(const float4*)(orow + k0 + 16);
        float4 g0 = *(const float4*)(gamma + k0);
        float4 g1 = *(const float4*)(gamma + k0 + 16);
        f[0]=(f16)(g0.x*a0.x); f[1]=(f16)(g0.y*a0.y); f[2]=(f16)(g0.z*a0.z); f[3]=(f16)(g0.w*a0.w);
        f[4]=(f16)(g1.x*a1.x); f[5]=(f16)(g1.y*a1.y); f[6]=(f16)(g1.z*a1.z); f[7]=(f16)(g1.w*a1.w);
      }
      *(f16x8*)(sOW + idx * 8) = f;
    }
    __syncthreads();

    float* sOut = (float*)&sFR[0][0][0][0];  // [2][4][16][16] floats = 8 KB overlay
    #pragma unroll
    for (int g = 0; g < 2; g++) {
      f32x4 aO = {0.f, 0.f, 0.f, 0.f};
      #pragma unroll
      for (int cp = 0; cp < 2; cp++) {
        f16x8 af;
        #pragma unroll
        for (int j = 0; j < 8; j++)
          af[j] = (f16)fmaf(rsF[g], (float)fin[g][cp][j], nmF[g]);
        f16x8 of = *(const f16x8*)(sOW + ((size_t)(2 * w + cp) * 64 + l) * 8);
        aO = __builtin_amdgcn_mfma_f32_16x16x32_f16(of, af, aO, 0, 0, 0);
      }
      #pragma unroll
      for (int r = 0; r < 4; r++)
        sOut[((g * 4 + w) * 16 + ml) * 16 + q * 4 + r] = aO[r];
    }
    __syncthreads();
    for (int idx = tid; idx < 32 * OUTD; idx += 256) {
      int m = idx / OUTD, o = idx - m * OUTD;
      int g = m >> 4, mm = m & 15;
      float s = 0.f;
      #pragma unroll
      for (int ww = 0; ww < 4; ww++) s += sOut[((g * 4 + ww) * 16 + mm) * 16 + o];
      out[(size_t)(base + m) * OUTD + o] = s + sOB[o];
    }
  }
}

extern "C" void kernel_launch(void* const* d_in, const int* in_sizes, int n_in,
                              void* d_out, int out_size, void* d_ws, size_t ws_size,
                              hipStream_t stream) {
  const float* x   = (const float*)d_in[0];
  const float* ew  = (const float*)d_in[1];
  const float* eb  = (const float*)d_in[2];
  const float* uw  = (const float*)d_in[3];
  const float* ub  = (const float*)d_in[4];
  const float* g   = (const float*)d_in[5];
  const float* be  = (const float*)d_in[6];
  const float* ow  = (const float*)d_in[7];
  const float* ob  = (const float*)d_in[8];
  float* out = (float*)d_out;

  const int B = in_sizes[0] / TST;      // 16384
  const int grid = B / 32;              // 512 blocks = 2/CU, one round
  hipLaunchKernelGGL(rnn_kernel, dim3(grid), dim3(256), 0, stream,
                     x, ew, eb, uw, ub, g, be, ow, ob, out);
}